// Round 6
// baseline (370.042 us; speedup 1.0000x reference)
//
#include <hip/hip_runtime.h>
#include <cstdint>
#include <cstddef>

#define N_NODES 50000
#define N_EDGES 800000
#define D 512
#define M_PAD 50048   // 391 * 128

typedef __bf16 bf16x8 __attribute__((ext_vector_type(8)));
typedef float floatx4 __attribute__((ext_vector_type(4)));

typedef const __attribute__((address_space(1))) unsigned int* gas_u32p;
typedef __attribute__((address_space(3))) unsigned int* las_u32p;

__device__ __forceinline__ unsigned short f2bf(float f) {
    unsigned int u = __builtin_bit_cast(unsigned int, f);
    u += 0x7FFFu + ((u >> 16) & 1u);
    return (unsigned short)(u >> 16);
}
__device__ __forceinline__ unsigned int pack_bf2(float lo, float hi) {
    return (unsigned)f2bf(lo) | ((unsigned)f2bf(hi) << 16);
}
__device__ __forceinline__ float bflo(unsigned int u) {
    return __builtin_bit_cast(float, u << 16);
}
__device__ __forceinline__ float bfhi(unsigned int u) {
    return __builtin_bit_cast(float, u & 0xFFFF0000u);
}

// ---- prep: weight (f32 [k][n]) -> WT bf16 [n][k]  AND  row_ptr build ----
__global__ __launch_bounds__(256) void k_prep(const float* __restrict__ w,
                                              unsigned short* __restrict__ wt,
                                              const int* __restrict__ rows,
                                              int* __restrict__ rp) {
    int b = blockIdx.x;
    if (b < 1024) {                       // WT convert: 262144 elems exact
        int id = b * 256 + threadIdx.x;
        int n = id >> 9, k = id & 511;
        wt[id] = f2bf(w[k * D + n]);
    } else {                              // row_ptr: lower_bound per node
        int i = (b - 1024) * 256 + threadIdx.x;
        if (i > N_NODES) return;
        int lo = 0, hi = N_EDGES;
        while (lo < hi) {
            int mid = (lo + hi) >> 1;
            if (rows[mid] < i) lo = mid + 1; else hi = mid;
        }
        rp[i] = lo;
    }
}

// ---- H = U(f32, cast->bf16 in-kernel) @ W -> bf16 [M_PAD x 512]
// A staged fp32->regs->cvt->ds_write; B staged via global_load_lds (16B).
// 1D grid, XCD swizzle: 4 N-tiles of one M-row sit 8 apart -> same XCD.
__global__ __launch_bounds__(256) void k_gemm(const float* __restrict__ U,
                                              const unsigned short* __restrict__ WT,
                                              unsigned short* __restrict__ H) {
    __shared__ unsigned short lA[128 * 32];
    __shared__ unsigned short lB[128 * 32];
    int b = blockIdx.x;                 // 1564 = 391 * 4
    int mt, nt;
    if (b < 1536) {                     // 48 groups of (8 m-tiles x 4 n-tiles)
        mt = (b >> 5) * 8 + (b & 7);
        nt = (b >> 3) & 3;
    } else {
        int r = b - 1536;
        mt = 384 + (r % 7);
        nt = r / 7;
    }
    const int tid  = threadIdx.x;
    const int wave = tid >> 6, lane = tid & 63;
    const int tileM0 = mt * 128;
    const int tileN0 = nt * 128;
    const int wr = wave >> 1, wc = wave & 1;

    // B staging (unchanged, async direct-to-LDS)
    const int lrow = lane >> 2, lslot = lane & 3;
    const int r0 = wave * 32;
    const int m0 = r0 + lrow,      m1 = r0 + 16 + lrow;
    const int q0 = (lslot - (m0 >> 1)) & 3;
    const int q1 = (lslot - (m1 >> 1)) & 3;
    const unsigned short* gB0 = WT + (size_t)(tileN0 + m0) * D + q0 * 8;
    const unsigned short* gB1 = WT + (size_t)(tileN0 + m1) * D + q1 * 8;
    unsigned short* lB0 = lB + r0 * 32;
    unsigned short* lB1 = lB + (r0 + 16) * 32;

    // A staging: thread -> row am = tid>>1, chunks aq, aq+1 (8 fp32 each)
    const int am = tid >> 1;
    const int aq = (tid & 1) * 2;
    const int arow = tileM0 + am;
    const bool aok = arow < N_NODES;
    const float* gA = U + (size_t)arow * D + aq * 8;
    unsigned short* lAw = lA + am * 32;
    const int s0 = (aq + (am >> 1)) & 3;
    const int s1 = (aq + 1 + (am >> 1)) & 3;

    floatx4 acc[4][4] = {};

    const int quad = lane >> 4, half = lane & 15;
    int offA[4], offB[4];
#pragma unroll
    for (int i = 0; i < 4; i++) {
        int m = wr * 64 + i * 16 + half;
        offA[i] = m * 32 + ((quad + (m >> 1)) & 3) * 8;
        int n = wc * 64 + i * 16 + half;
        offB[i] = n * 32 + ((quad + (n >> 1)) & 3) * 8;
    }

    for (int k0 = 0; k0 < D; k0 += 32) {
        // A fp32 prefetch to registers (issued before the barrier)
        float4 fa0, fa1, fb0, fb1;
        if (aok) {
            const float4* p = (const float4*)(gA + k0);
            fa0 = p[0]; fa1 = p[1]; fb0 = p[2]; fb1 = p[3];
        } else {
            fa0 = fa1 = fb0 = fb1 = make_float4(0.f, 0.f, 0.f, 0.f);
        }
        __syncthreads();   // previous iteration's LDS reads complete
        __builtin_amdgcn_global_load_lds((gas_u32p)(gB0 + k0), (las_u32p)lB0, 16, 0, 0);
        __builtin_amdgcn_global_load_lds((gas_u32p)(gB1 + k0), (las_u32p)lB1, 16, 0, 0);
        uint4 pk0, pk1;
        pk0.x = pack_bf2(fa0.x, fa0.y); pk0.y = pack_bf2(fa0.z, fa0.w);
        pk0.z = pack_bf2(fa1.x, fa1.y); pk0.w = pack_bf2(fa1.z, fa1.w);
        pk1.x = pack_bf2(fb0.x, fb0.y); pk1.y = pack_bf2(fb0.z, fb0.w);
        pk1.z = pack_bf2(fb1.x, fb1.y); pk1.w = pack_bf2(fb1.z, fb1.w);
        *(uint4*)(lAw + s0 * 8) = pk0;
        *(uint4*)(lAw + s1 * 8) = pk1;
        __syncthreads();

        bf16x8 af[4], bfr[4];
#pragma unroll
        for (int i = 0; i < 4; i++) {
            af[i]  = *(const bf16x8*)(lA + offA[i]);
            bfr[i] = *(const bf16x8*)(lB + offB[i]);
        }
#pragma unroll
        for (int i = 0; i < 4; i++)
#pragma unroll
            for (int j = 0; j < 4; j++)
                acc[i][j] = __builtin_amdgcn_mfma_f32_16x16x32_bf16(af[i], bfr[j], acc[i][j], 0, 0, 0);
    }

    // epilogue: C/D layout col = lane&15, row = quad*4 + r (row-major H)
#pragma unroll
    for (int i = 0; i < 4; i++) {
        int gm0 = tileM0 + wr * 64 + i * 16 + quad * 4;
#pragma unroll
        for (int j = 0; j < 4; j++) {
            int gn = tileN0 + wc * 64 + j * 16 + half;
#pragma unroll
            for (int r = 0; r < 4; r++) {
                H[(size_t)(gm0 + r) * D + gn] = f2bf(acc[i][j][r]);
            }
        }
    }
}

// ---- out[row] = relu( sum_e vals[e] * h[cols[e]] ), one wave per node.
// R3-proven structure; two half-dispatches keep other kernels visible in
// the top-5 profile.
__global__ __launch_bounds__(256) void k_scatter_half(const int* __restrict__ rp,
                                                      const int* __restrict__ cols,
                                                      const float* __restrict__ vals,
                                                      const unsigned short* __restrict__ H,
                                                      float* __restrict__ out,
                                                      int node_base) {
    int node = node_base + (int)((blockIdx.x * 256 + threadIdx.x) >> 6);
    int lane = threadIdx.x & 63;
    if (node >= N_NODES) return;
    int s = rp[node], e = rp[node + 1];
    float a0 = 0.f, a1 = 0.f, a2 = 0.f, a3 = 0.f;
    float a4 = 0.f, a5 = 0.f, a6 = 0.f, a7 = 0.f;
    const uint4* H4 = (const uint4*)H;          // row c starts at index c*64
    const int lq = lane;                        // uint4 slot within row
    for (int t = s; t < e; t += 4) {
        int last = e - 1;
        int t1 = t + 1 < e ? t + 1 : last;
        int t2 = t + 2 < e ? t + 2 : last;
        int t3 = t + 3 < e ? t + 3 : last;
        int c0 = cols[t],  c1 = cols[t1], c2 = cols[t2], c3 = cols[t3];
        float v0 = vals[t];
        float v1 = t + 1 < e ? vals[t1] : 0.f;
        float v2 = t + 2 < e ? vals[t2] : 0.f;
        float v3 = t + 3 < e ? vals[t3] : 0.f;
        uint4 d0 = H4[(size_t)c0 * 64 + lq];
        uint4 d1 = H4[(size_t)c1 * 64 + lq];
        uint4 d2 = H4[(size_t)c2 * 64 + lq];
        uint4 d3 = H4[(size_t)c3 * 64 + lq];
        a0 = fmaf(v0, bflo(d0.x), a0); a1 = fmaf(v0, bfhi(d0.x), a1);
        a2 = fmaf(v0, bflo(d0.y), a2); a3 = fmaf(v0, bfhi(d0.y), a3);
        a4 = fmaf(v0, bflo(d0.z), a4); a5 = fmaf(v0, bfhi(d0.z), a5);
        a6 = fmaf(v0, bflo(d0.w), a6); a7 = fmaf(v0, bfhi(d0.w), a7);
        a0 = fmaf(v1, bflo(d1.x), a0); a1 = fmaf(v1, bfhi(d1.x), a1);
        a2 = fmaf(v1, bflo(d1.y), a2); a3 = fmaf(v1, bfhi(d1.y), a3);
        a4 = fmaf(v1, bflo(d1.z), a4); a5 = fmaf(v1, bfhi(d1.z), a5);
        a6 = fmaf(v1, bflo(d1.w), a6); a7 = fmaf(v1, bfhi(d1.w), a7);
        a0 = fmaf(v2, bflo(d2.x), a0); a1 = fmaf(v2, bfhi(d2.x), a1);
        a2 = fmaf(v2, bflo(d2.y), a2); a3 = fmaf(v2, bfhi(d2.y), a3);
        a4 = fmaf(v2, bflo(d2.z), a4); a5 = fmaf(v2, bfhi(d2.z), a5);
        a6 = fmaf(v2, bflo(d2.w), a6); a7 = fmaf(v2, bfhi(d2.w), a7);
        a0 = fmaf(v3, bflo(d3.x), a0); a1 = fmaf(v3, bfhi(d3.x), a1);
        a2 = fmaf(v3, bflo(d3.y), a2); a3 = fmaf(v3, bfhi(d3.y), a3);
        a4 = fmaf(v3, bflo(d3.z), a4); a5 = fmaf(v3, bfhi(d3.z), a5);
        a6 = fmaf(v3, bflo(d3.w), a6); a7 = fmaf(v3, bfhi(d3.w), a7);
    }
    float* o = out + (size_t)node * D + (size_t)lane * 8;
    *(float4*)o       = make_float4(fmaxf(a0, 0.f), fmaxf(a1, 0.f), fmaxf(a2, 0.f), fmaxf(a3, 0.f));
    *(float4*)(o + 4) = make_float4(fmaxf(a4, 0.f), fmaxf(a5, 0.f), fmaxf(a6, 0.f), fmaxf(a7, 0.f));
}

extern "C" void kernel_launch(void* const* d_in, const int* in_sizes, int n_in,
                              void* d_out, int out_size, void* d_ws, size_t ws_size,
                              hipStream_t stream) {
    const int*   adj_rows = (const int*)d_in[0];
    const int*   adj_cols = (const int*)d_in[1];
    const float* adj_vals = (const float*)d_in[2];
    const float* u_f      = (const float*)d_in[3];
    const float* weight   = (const float*)d_in[4];
    float* out = (float*)d_out;

    char* ws = (char*)d_ws;
    unsigned short* wt_bf = (unsigned short*)ws;                       // 524,288 B
    unsigned short* h_bf  = (unsigned short*)(ws + 524288);            // 51,249,152 B
    int* rowptr           = (int*)(ws + 524288 + 51249152);            // 200,004 B

    hipLaunchKernelGGL(k_prep,  dim3(1220), dim3(256), 0, stream, weight, wt_bf, adj_rows, rowptr);
    hipLaunchKernelGGL(k_gemm,  dim3(1564), dim3(256), 0, stream, u_f, wt_bf, h_bf);
    hipLaunchKernelGGL(k_scatter_half, dim3(6250), dim3(256), 0, stream, rowptr, adj_cols, adj_vals, h_bf, out, 0);
    hipLaunchKernelGGL(k_scatter_half, dim3(6250), dim3(256), 0, stream, rowptr, adj_cols, adj_vals, h_bf, out, 25000);
}